// Round 8
// baseline (403.937 us; speedup 1.0000x reference)
//
#include <hip/hip_runtime.h>

// Problem constants (B=2, S=2048, HIDDEN=1024, HEADS=16, HEAD_DIM=64, ROT=16)
#define S_ 2048
#define EPSF 1e-8f
#define SCALEF 0.125f

typedef short bf16x8 __attribute__((ext_vector_type(8)));
typedef float f32x4 __attribute__((ext_vector_type(4)));

__device__ __forceinline__ unsigned short f2bf(float f){
  unsigned int u = __float_as_uint(f);
  u = (u + 0x7fffu + ((u >> 16) & 1u)) >> 16;
  return (unsigned short)u;
}
__device__ __forceinline__ float bf2f(unsigned short h){
  return __uint_as_float(((unsigned int)h) << 16);
}
__device__ __forceinline__ unsigned short f2bf_trunc(float f){
  return (unsigned short)(__float_as_uint(f) >> 16);
}

// ---------------- 1a: fp32 -> bf16 convert of hidden_states [4096][1024]
__global__ void k_conv_a(const float* __restrict__ A, unsigned short* __restrict__ Ab){
  int i = (blockIdx.x * 256 + threadIdx.x) * 4;   // exact fit: 4096 blocks
  float4 v = *(const float4*)(A + i);
  ushort4 o; o.x=f2bf(v.x); o.y=f2bf(v.y); o.z=f2bf(v.z); o.w=f2bf(v.w);
  *(ushort4*)(Ab + i) = o;
}

// ---------------- 1b: Wqkv cols [0,2048) -> WT bf16 [2048][1024] (transposed)
__global__ void k_conv_wt(const float* __restrict__ W, unsigned short* __restrict__ WT){
  __shared__ float t[32][33];
  int nt = blockIdx.x, kt = blockIdx.y;
  int tx = threadIdx.x & 31, ty = threadIdx.x >> 5;   // 32 x 8
  #pragma unroll
  for (int r = 0; r < 32; r += 8)
    t[ty + r][tx] = W[(size_t)(kt*32 + ty + r)*3072 + nt*32 + tx];
  __syncthreads();
  #pragma unroll
  for (int r = 0; r < 32; r += 8)
    WT[(size_t)(nt*32 + ty + r)*1024 + kt*32 + tx] = f2bf(t[tx][ty + r]);
}

// ---------------- 1c: v0[b,h,d] = hs[b,0,:] @ Wqkv[:, 2048+h*64+d] + bqkv
__global__ void k_v0(const float* __restrict__ hs, const float* __restrict__ Wqkv,
                     const float* __restrict__ bqkv, float* __restrict__ v0){
  int bh = blockIdx.x; int b = bh >> 4;
  int d = threadIdx.x & 63, kc = threadIdx.x >> 6;
  const float* x = hs + (size_t)b * S_ * 1024;
  int col = 2048 + (bh & 15)*64 + d;
  float acc = 0.f;
  #pragma unroll 8
  for (int k = kc*256; k < kc*256 + 256; ++k)
    acc = fmaf(x[k], Wqkv[(size_t)k*3072 + col], acc);
  __shared__ float red[4][64];
  red[kc][d] = acc;
  __syncthreads();
  if (kc == 0)
    v0[bh*64 + d] = red[0][d] + red[1][d] + red[2][d] + red[3][d] + bqkv[col];
}

// ---------------- 2: QK projection GEMM, M=4096 N=2048 K=1024, bf16 MFMA
#define GSTRIDE 72   // LDS row stride in bf16 elems
__launch_bounds__(256)
__global__ void k_gemm_qk(const unsigned short* __restrict__ Ab,
                          const unsigned short* __restrict__ WT,
                          const float* __restrict__ bqkv,
                          unsigned short* __restrict__ Qb,
                          unsigned short* __restrict__ Kb){
  __shared__ unsigned short At[128*GSTRIDE];
  __shared__ unsigned short Bt[128*GSTRIDE];
  const int m0 = blockIdx.y * 128, n0 = blockIdx.x * 128;
  const int w = threadIdx.x >> 6, l = threadIdx.x & 63;
  const int wr = w >> 1, wc = w & 1;
  f32x4 acc[4][4];
  #pragma unroll
  for (int i = 0; i < 4; ++i)
    #pragma unroll
    for (int j = 0; j < 4; ++j) acc[i][j] = (f32x4){0.f,0.f,0.f,0.f};

  const int srow = threadIdx.x >> 1;
  const int sseg = (threadIdx.x & 1) * 2;

  for (int kt = 0; kt < 1024; kt += 32){
    int4 va0 = *(const int4*)(Ab + (size_t)(m0+srow)*1024 + kt + sseg*8);
    int4 va1 = *(const int4*)(Ab + (size_t)(m0+srow)*1024 + kt + sseg*8 + 8);
    int4 vb0 = *(const int4*)(WT + (size_t)(n0+srow)*1024 + kt + sseg*8);
    int4 vb1 = *(const int4*)(WT + (size_t)(n0+srow)*1024 + kt + sseg*8 + 8);
    *(int4*)&At[srow*GSTRIDE + sseg*8]     = va0;
    *(int4*)&At[srow*GSTRIDE + sseg*8 + 8] = va1;
    *(int4*)&Bt[srow*GSTRIDE + sseg*8]     = vb0;
    *(int4*)&Bt[srow*GSTRIDE + sseg*8 + 8] = vb1;
    __syncthreads();
    bf16x8 af[4], bf[4];
    #pragma unroll
    for (int i = 0; i < 4; ++i)
      af[i] = *(const bf16x8*)&At[(wr*64 + i*16 + (l&15))*GSTRIDE + (l>>4)*8];
    #pragma unroll
    for (int j = 0; j < 4; ++j)
      bf[j] = *(const bf16x8*)&Bt[(wc*64 + j*16 + (l&15))*GSTRIDE + (l>>4)*8];
    #pragma unroll
    for (int i = 0; i < 4; ++i)
      #pragma unroll
      for (int j = 0; j < 4; ++j)
        acc[i][j] = __builtin_amdgcn_mfma_f32_16x16x32_bf16(af[i], bf[j], acc[i][j], 0, 0, 0);
    __syncthreads();
  }
  #pragma unroll
  for (int i = 0; i < 4; ++i){
    #pragma unroll
    for (int j = 0; j < 4; ++j){
      #pragma unroll
      for (int r = 0; r < 4; ++r){
        int m = m0 + wr*64 + i*16 + (l>>4)*4 + r;
        int n = n0 + wc*64 + j*16 + (l&15);
        float v = acc[i][j][r] + bqkv[n];
        int b = m >> 11, s = m & 2047;
        int tsel = n >> 10; int nq = n & 1023;
        int h = nq >> 6, d = nq & 63;
        unsigned short* dst = tsel ? Kb : Qb;
        dst[((size_t)(b*16 + h)*S_ + s)*64 + d] = f2bf(v);
      }
    }
  }
}

// ---------------- 3: RoPE in place on Q,K (first 16 dims per head row)
__global__ void k_rope(unsigned short* __restrict__ Qb, unsigned short* __restrict__ Kb,
                       const int* __restrict__ pos_ids){
  int idx = blockIdx.x * 256 + threadIdx.x;   // 2^20 total: t(1) bh(5) s(11) d(3)
  int d = idx & 7;
  int s = (idx >> 3) & 2047;
  int bh = (idx >> 14) & 31;
  int tsel = idx >> 19;
  unsigned short* X = tsel ? Kb : Qb;
  size_t base = ((size_t)bh * S_ + s) * 64;
  float pos = (float)pos_ids[s];
  float freq = exp2f(-1.6609640474436813f * (float)d);  // 10000^(-d/8)
  float th = pos * freq;
  float sn = __sinf(th), cn = __cosf(th);
  float x0 = bf2f(X[base + d]), x1 = bf2f(X[base + d + 8]);
  X[base + d]     = f2bf(x0 * cn - x1 * sn);
  X[base + d + 8] = f2bf(x1 * cn + x0 * sn);
}

// ---------------- 4a: full-chip E + rinv precompute.
// WG per (bi, bh). E tile (bi,bj) at Eg[(bh*528 + tri(bi)+bj)*4096],
// quarter-major [w][16 rows][64 cols]. rinv_i = 1/(D+eps(D+E_ii)).
#define KST2 66
__launch_bounds__(256, 4)
__global__ void k_scores(const unsigned short* __restrict__ Qb,
                         const unsigned short* __restrict__ Kb,
                         unsigned short* __restrict__ Eg,
                         float* __restrict__ rinvg){
  __shared__ unsigned short Ks[64*KST2];
  __shared__ float dsh[4][16];
  const int bi = blockIdx.x >> 5, bh = blockIdx.x & 31;
  const unsigned short* Qh = Qb + (size_t)bh * S_ * 64;
  const unsigned short* Kh = Kb + (size_t)bh * S_ * 64;
  const int tid = threadIdx.x, w = tid >> 6, l = tid & 63;
  const int lq = l & 15, lh = l >> 4;
  const unsigned short* qp = Qh + (size_t)(bi*64 + w*16 + lq)*64 + lh*8;
  bf16x8 qf0 = *(const bf16x8*)(qp);
  bf16x8 qf1 = *(const bf16x8*)(qp + 32);
  float dacc[4] = {0.f,0.f,0.f,0.f};
  unsigned short* Etile0 = Eg + ((size_t)bh*528 + (size_t)(bi*(bi+1)/2))*4096;

  for (int bj = 0; bj <= bi; ++bj){
    __syncthreads();
    {
      int srow = tid >> 2, sc = (tid & 3)*16;
      const unsigned short* src = Kh + (size_t)(bj*64 + srow)*64 + sc;
      *(int4*)&Ks[srow*KST2 + sc]     = *(const int4*)(src);
      *(int4*)&Ks[srow*KST2 + sc + 8] = *(const int4*)(src + 8);
    }
    __syncthreads();
    unsigned short* Et = Etile0 + (size_t)bj*4096 + w*1024;
    const bool diag = (bj == bi);
    #pragma unroll
    for (int ct = 0; ct < 4; ++ct){
      bf16x8 b0 = *(const bf16x8*)&Ks[(ct*16 + lq)*KST2 + lh*8];
      bf16x8 b1 = *(const bf16x8*)&Ks[(ct*16 + lq)*KST2 + 32 + lh*8];
      f32x4 a = (f32x4){0.f,0.f,0.f,0.f};
      a = __builtin_amdgcn_mfma_f32_16x16x32_bf16(qf0, b0, a, 0, 0, 0);
      a = __builtin_amdgcn_mfma_f32_16x16x32_bf16(qf1, b1, a, 0, 0, 0);
      #pragma unroll
      for (int r = 0; r < 4; ++r){
        float e = __expf(a[r] * SCALEF);
        unsigned short eb = f2bf_trunc(e);
        int rrow = lh*4 + r, col = ct*16 + lq;
        Et[rrow*64 + col] = eb;
        float ev = bf2f(eb);
        int grow = w*16 + rrow;                 // global row within 64-block
        if (!diag || col < grow) dacc[r] += ev;
        if (diag && col == grow) dsh[w][rrow] = ev;
      }
    }
  }
  __syncthreads();
  #pragma unroll
  for (int r = 0; r < 4; ++r){
    float d = dacc[r];
    #pragma unroll
    for (int mm = 1; mm < 16; mm <<= 1) d += __shfl_xor(d, mm);
    float dE = dsh[w][lh*4 + r];
    float den = fmaf(EPSF, d + dE, d);
    float rv = 1.0f / den;
    if (lq == 0)
      rinvg[(size_t)bh*S_ + bi*64 + w*16 + lh*4 + r] = rv;
  }
}

// ---------------- 4b: pipelined sequential recurrence. One WG (16 waves)/head.
// Iteration bj, Phase A (concurrent): wave0 solves block bj; waves 1-15 fold
// column bj-1 into rows >= bj+1 with ALL unit loads batch-issued upfront
// (one exposed latency, not 8); waves 4-7 pre-issue the urgent tile loads
// (col bj, row bj+1); wave 15 prefetches diag bj+1. Phase B: urgent fold.
#define MAXU 8
__launch_bounds__(1024, 4)
__global__ void k_recur2(const unsigned short* __restrict__ Eg,
                         const float* __restrict__ rinvg,
                         float* __restrict__ c_g){
  __shared__ float Pa[S_];                 // running P per row
  __shared__ float rs[S_];                 // rinv preload
  __shared__ float cs[2][64];              // c double-buffer
  __shared__ unsigned short Dsh[2][4096];  // diag tile double-buffer (swizzled)
  const int bh = blockIdx.x;
  const unsigned short* Eh = Eg + (size_t)bh * 528 * 4096;
  const int tid = threadIdx.x, w = tid >> 6, l = tid & 63;
  const int lq = l & 15, lh = l >> 4;
  Pa[tid] = 0.f; Pa[tid + 1024] = 0.f;
  rs[tid] = rinvg[(size_t)bh*S_ + tid];
  rs[tid + 1024] = rinvg[(size_t)bh*S_ + tid + 1024];
  if (w == 15){   // prefetch diag tile (0,0), XOR-swizzled rows
    #pragma unroll
    for (int eb = 0; eb < 8; ++eb){
      int bofs = ((eb*64 + l)*16) ^ (((l>>3)&7)<<4);
      *(int4*)((char*)Dsh[0] + bofs) = *(const int4*)(Eh + l*64 + eb*8);
    }
  }
  __syncthreads();

  for (int bj = 0; bj < 32; ++bj){
    const int cur = bj & 1;

    // ---- Phase A ----
    // urgent pre-issue (waves 4-7): tile (bj+1, col bj), quarter w-4
    bf16x8 ug0, ug1;
    const bool hasU = (bj < 31) && (w >= 4) && (w < 8);
    if (hasU){
      int bn = bj + 1;
      const unsigned short* tp =
          Eh + ((size_t)(bn*(bn+1)/2) + bj)*4096 + (size_t)(w-4)*1024;
      ug0 = *(const bf16x8*)(tp + lq*64 + lh*8);
      ug1 = *(const bf16x8*)(tp + lq*64 + 32 + lh*8);
    }
    // wave 15: prefetch next diag tile
    if (w == 15 && bj < 31){
      int bn = bj + 1;
      const unsigned short* src = Eh + ((size_t)(bn*(bn+1)/2) + bn)*4096;
      #pragma unroll
      for (int eb = 0; eb < 8; ++eb){
        int bofs = ((eb*64 + l)*16) ^ (((l>>3)&7)<<4);
        *(int4*)((char*)Dsh[cur^1] + bofs) = *(const int4*)(src + l*64 + eb*8);
      }
    }
    // wave 0: solve block bj
    if (w == 0){
      const int rr = l;
      bf16x8 er[8];
      #pragma unroll
      for (int eb = 0; eb < 8; ++eb){
        int bofs = ((eb*64 + rr)*16) ^ (((rr>>3)&7)<<4);
        er[eb] = *(const bf16x8*)((const char*)Dsh[cur] + bofs);
      }
      float rinv = rs[bj*64 + rr];
      float Pl = Pa[bj*64 + rr];
      float cval = 0.f;
      #pragma unroll
      for (int eb = 0; eb < 8; ++eb){
        #pragma unroll
        for (int e = 0; e < 8; ++e){
          int r = eb*8 + e;
          float t = Pl * rinv;
          float cr = __uint_as_float(
              (unsigned)__builtin_amdgcn_readlane(__float_as_uint(t), r));
          if (bj == 0 && r == 0) cr = 1.0f;
          if (rr == r) cval = cr;
          float m = (rr > r) ? bf2f((unsigned short)er[eb][e]) : 0.f;
          Pl = fmaf(m, cr, Pl);
        }
      }
      cs[cur][rr] = cval;
      c_g[((size_t)(bh >> 4)*S_ + (bj*64 + rr))*16 + (bh & 15)] = cval;
    } else if (bj >= 1){
      // deferred fold of column bj-1 into rows >= bj+1 (waves 1..15),
      // batch-issued loads: one exposed latency for up to MAXU units.
      const int nu_d = (31 - bj) * 4;
      const int colj = bj - 1;
      bf16x8 dc0 = (bf16x8){0,0,0,0,0,0,0,0};
      bf16x8 dc1 = (bf16x8){0,0,0,0,0,0,0,0};
      if (lq == 0){
        #pragma unroll
        for (int e = 0; e < 8; ++e){
          dc0[e] = (short)f2bf(cs[cur^1][lh*8 + e]);
          dc1[e] = (short)f2bf(cs[cur^1][32 + lh*8 + e]);
        }
      }
      bf16x8 p0[MAXU], p1[MAXU];
      #pragma unroll
      for (int uu = 0; uu < MAXU; ++uu){
        int u = (w - 1) + uu*15;
        if (u < nu_d){
          int bi = bj + 1 + (u >> 2);
          const unsigned short* tp =
              Eh + ((size_t)(bi*(bi+1)/2) + colj)*4096 + (size_t)(u&3)*1024;
          p0[uu] = *(const bf16x8*)(tp + lq*64 + lh*8);
          p1[uu] = *(const bf16x8*)(tp + lq*64 + 32 + lh*8);
        }
      }
      #pragma unroll
      for (int uu = 0; uu < MAXU; ++uu){
        int u = (w - 1) + uu*15;
        if (u < nu_d){
          f32x4 o = (f32x4){0.f,0.f,0.f,0.f};
          o = __builtin_amdgcn_mfma_f32_16x16x32_bf16(p0[uu], dc0, o, 0, 0, 0);
          o = __builtin_amdgcn_mfma_f32_16x16x32_bf16(p1[uu], dc1, o, 0, 0, 0);
          if (lq == 0){
            int bi = bj + 1 + (u >> 2);
            float* base = Pa + bi*64 + (u&3)*16 + lh*4;
            float4 v = *(float4*)base;
            v.x += o[0]; v.y += o[1]; v.z += o[2]; v.w += o[3];
            *(float4*)base = v;
          }
        }
      }
    }
    __syncthreads();   // cs[cur] visible; deferred folds done

    // ---- Phase B: urgent fold (waves 4-7) ----
    if (hasU){
      bf16x8 c0f = (bf16x8){0,0,0,0,0,0,0,0};
      bf16x8 c1f = (bf16x8){0,0,0,0,0,0,0,0};
      if (lq == 0){
        #pragma unroll
        for (int e = 0; e < 8; ++e){
          c0f[e] = (short)f2bf(cs[cur][lh*8 + e]);
          c1f[e] = (short)f2bf(cs[cur][32 + lh*8 + e]);
        }
      }
      f32x4 o = (f32x4){0.f,0.f,0.f,0.f};
      o = __builtin_amdgcn_mfma_f32_16x16x32_bf16(ug0, c0f, o, 0, 0, 0);
      o = __builtin_amdgcn_mfma_f32_16x16x32_bf16(ug1, c1f, o, 0, 0, 0);
      if (lq == 0){
        float* base = Pa + (bj+1)*64 + (w-4)*16 + lh*4;
        float4 v = *(float4*)base;
        v.x += o[0]; v.y += o[1]; v.z += o[2]; v.w += o[3];
        *(float4*)base = v;
      }
    }
    __syncthreads();   // urgent fold + Dsh[cur^1] ready for next solve
  }
}

// ---------------- 5a: U[b,h,n] = sum_d v0[b,h,d] * Wd[h*64+d][n]
__global__ void k_u(const float* __restrict__ v0, const float* __restrict__ Wd,
                    float* __restrict__ U){
  int bh = blockIdx.x; int h = bh & 15;
  __shared__ float vsh[64];
  if (threadIdx.x < 64) vsh[threadIdx.x] = v0[bh*64 + threadIdx.x];
  __syncthreads();
  for (int n = threadIdx.x; n < 1024; n += 256){
    float acc = 0.f;
    #pragma unroll 8
    for (int d = 0; d < 64; ++d) acc = fmaf(vsh[d], Wd[(size_t)(h*64 + d)*1024 + n], acc);
    U[(size_t)bh*1024 + n] = acc;
  }
}

// ---------------- 5b: out[b,s,n] = bd[n] + sum_h c[b,s,h] * U[b,h,n]
__global__ void k_out(const float* __restrict__ c_g, const float* __restrict__ U,
                      const float* __restrict__ bd, float* __restrict__ out){
  int bs = blockIdx.x; int b = bs >> 11;
  __shared__ float ch[16];
  if (threadIdx.x < 16) ch[threadIdx.x] = c_g[(size_t)bs*16 + threadIdx.x];
  __syncthreads();
  int n = threadIdx.x * 4;
  float4 acc = *(const float4*)(bd + n);
  #pragma unroll
  for (int h = 0; h < 16; ++h){
    float cc = ch[h];
    float4 u = *(const float4*)(U + ((size_t)(b*16 + h))*1024 + n);
    acc.x = fmaf(cc, u.x, acc.x); acc.y = fmaf(cc, u.y, acc.y);
    acc.z = fmaf(cc, u.z, acc.z); acc.w = fmaf(cc, u.w, acc.w);
  }
  *(float4*)(out + (size_t)bs*1024 + n) = acc;
}

extern "C" void kernel_launch(void* const* d_in, const int* in_sizes, int n_in,
                              void* d_out, int out_size, void* d_ws, size_t ws_size,
                              hipStream_t stream) {
  const float* hs   = (const float*)d_in[0];   // [2][2048][1024]
  const int*   pos  = (const int*)d_in[1];     // [2048]
  const float* Wqkv = (const float*)d_in[2];   // [1024][3072]
  const float* bqkv = (const float*)d_in[3];   // [3072]
  const float* Wd   = (const float*)d_in[4];   // [1024][1024]
  const float* bd   = (const float*)d_in[5];   // [1024]
  float* out = (float*)d_out;

  // workspace layout
  char* ws = (char*)d_ws;
  unsigned short* Ab = (unsigned short*)(ws);                       // 8 MB
  unsigned short* WT = (unsigned short*)(ws + (8u<<20));            // 4 MB
  unsigned short* Qb = (unsigned short*)(ws + (12u<<20));           // 8 MB
  unsigned short* Kb = (unsigned short*)(ws + (20u<<20));           // 8 MB
  float* v0  = (float*)(ws + (28u<<20));                            // 8 KB
  float* c_g = (float*)(ws + (28u<<20) + (1u<<16));                 // 256 KB
  float* U   = (float*)(ws + (28u<<20) + (1u<<16) + (1u<<18));      // 128 KB
  float* rinvg = (float*)(ws + (28u<<20) + (1u<<19));               // 256 KB
  unsigned short* Eg = (unsigned short*)(ws + (29u<<20));           // 132 MB

  k_conv_a <<<4096, 256, 0, stream>>>(hs, Ab);
  k_conv_wt<<<dim3(64, 32), 256, 0, stream>>>(Wqkv, WT);
  k_v0     <<<32, 256, 0, stream>>>(hs, Wqkv, bqkv, v0);
  k_gemm_qk<<<dim3(16, 32), 256, 0, stream>>>(Ab, WT, bqkv, Qb, Kb);
  k_rope   <<<4096, 256, 0, stream>>>(Qb, Kb, pos);
  k_scores <<<1024, 256, 0, stream>>>(Qb, Kb, Eg, rinvg);
  k_recur2 <<<32, 1024, 0, stream>>>(Eg, rinvg, c_g);
  k_u      <<<32, 256, 0, stream>>>(v0, Wd, U);
  k_out    <<<4096, 256, 0, stream>>>(c_g, U, bd, out);
}